// Round 1
// baseline (2504.027 us; speedup 1.0000x reference)
//
#include <hip/hip_runtime.h>

namespace {
constexpr int DM = 1024;   // d_model
constexpr int NH = 16;     // heads
constexpr int HD = 64;     // head dim
constexpr int SEQ = 2048;
constexpr int NB = 4;      // batch
constexpr int ROWS = NB * SEQ;  // 8192

// ---------------------------------------------------------------------------
// Per-head projection GEMM: OUT[b,h,s,k] = sum_d X[b,s,d] * W[h,d,k] + bias[h,k]
// X: [ROWS, DM] row-major; W: [NH, DM, HD]; OUT: [NB*NH, SEQ, HD]
// grid (ROWS/64, NH), block 256; 64x64 tile, 4x4 per thread, BK=32
// ---------------------------------------------------------------------------
__global__ __launch_bounds__(256) void proj_qkv(
    const float* __restrict__ X, const float* __restrict__ W,
    const float* __restrict__ bias, float* __restrict__ OUT)
{
  __shared__ float As[32][68];   // k-major: As[kk][row] (pad 68 keeps f4 align)
  __shared__ float Bs[32][64];   // Bs[kk][col]
  const int tid = threadIdx.x;
  const int tx = tid & 15, ty = tid >> 4;
  const int row0 = blockIdx.x * 64;
  const int h = blockIdx.y;
  const float* __restrict__ Wh = W + (size_t)h * DM * HD;
  float acc[4][4] = {};

  #pragma unroll 1
  for (int k0 = 0; k0 < DM; k0 += 32) {
    #pragma unroll
    for (int it = 0; it < 2; ++it) {
      const int i = tid + it * 256;            // 0..511
      const int r = i >> 3, c = (i & 7) * 4;   // 64 rows x 32 k
      const float4 v = *reinterpret_cast<const float4*>(
          X + (size_t)(row0 + r) * DM + k0 + c);
      As[c + 0][r] = v.x; As[c + 1][r] = v.y;
      As[c + 2][r] = v.z; As[c + 3][r] = v.w;
    }
    #pragma unroll
    for (int it = 0; it < 2; ++it) {
      const int i = tid + it * 256;            // 0..511
      const int kk = i >> 4, j = (i & 15) * 4; // 32 k x 64 cols
      *reinterpret_cast<float4*>(&Bs[kk][j]) =
          *reinterpret_cast<const float4*>(Wh + (size_t)(k0 + kk) * HD + j);
    }
    __syncthreads();
    #pragma unroll
    for (int kk = 0; kk < 32; ++kk) {
      const float4 a = *reinterpret_cast<const float4*>(&As[kk][ty * 4]);
      const float4 b = *reinterpret_cast<const float4*>(&Bs[kk][tx * 4]);
      const float av[4] = {a.x, a.y, a.z, a.w};
      const float bv[4] = {b.x, b.y, b.z, b.w};
      #pragma unroll
      for (int i = 0; i < 4; ++i)
        #pragma unroll
        for (int j = 0; j < 4; ++j) acc[i][j] += av[i] * bv[j];
    }
    __syncthreads();
  }

  const float4 bz = *reinterpret_cast<const float4*>(bias + h * HD + tx * 4);
  #pragma unroll
  for (int i = 0; i < 4; ++i) {
    const int rg = row0 + ty * 4 + i;          // global row in [0, ROWS)
    const int b = rg >> 11, srow = rg & (SEQ - 1);
    float4 o;
    o.x = acc[i][0] + bz.x; o.y = acc[i][1] + bz.y;
    o.z = acc[i][2] + bz.z; o.w = acc[i][3] + bz.w;
    *reinterpret_cast<float4*>(
        OUT + ((size_t)(b * NH + h) * SEQ + srow) * HD + tx * 4) = o;
  }
}

// ---------------------------------------------------------------------------
// Flash-style attention, one query row per thread.
// Q,K,V: [NB*NH, SEQ, HD]; AO: [NB, SEQ, DM] (writes column slice h*64..+63)
// grid (SEQ/256, NH, NB), block 256
// ---------------------------------------------------------------------------
__global__ __launch_bounds__(256) void attn(
    const float* __restrict__ Q, const float* __restrict__ K,
    const float* __restrict__ V, float* __restrict__ AO)
{
  __shared__ float Ks[64][64];
  __shared__ float Vs[64][64];
  const int tid = threadIdx.x;
  const int h = blockIdx.y, b = blockIdx.z;
  const int row = blockIdx.x * 256 + tid;
  const size_t bh = (size_t)(b * NH + h) * SEQ;

  float4 q4[16];
  {
    const float* qp = Q + (bh + row) * HD;
    #pragma unroll
    for (int c = 0; c < 16; ++c) q4[c] = reinterpret_cast<const float4*>(qp)[c];
  }

  float m = -1e30f, l = 0.f;
  float4 o4[16] = {};

  #pragma unroll 1
  for (int kt = 0; kt < SEQ / 64; ++kt) {
    #pragma unroll
    for (int it = 0; it < 4; ++it) {
      const int i = tid + it * 256;            // 0..1023
      const int r = i >> 4, c = (i & 15) * 4;  // 64 rows x 64 cols
      const size_t g = (bh + (size_t)kt * 64 + r) * HD + c;
      *reinterpret_cast<float4*>(&Ks[r][c]) = *reinterpret_cast<const float4*>(K + g);
      *reinterpret_cast<float4*>(&Vs[r][c]) = *reinterpret_cast<const float4*>(V + g);
    }
    __syncthreads();

    #pragma unroll 1
    for (int jc = 0; jc < 4; ++jc) {
      float s[16];
      float tmax = -1e30f;
      #pragma unroll
      for (int jj = 0; jj < 16; ++jj) {
        const int j = jc * 16 + jj;
        float a0 = 0.f, a1 = 0.f, a2 = 0.f, a3 = 0.f;
        const float4* kr = reinterpret_cast<const float4*>(&Ks[j][0]);
        #pragma unroll
        for (int c = 0; c < 16; ++c) {
          const float4 kv = kr[c];
          a0 += q4[c].x * kv.x; a1 += q4[c].y * kv.y;
          a2 += q4[c].z * kv.z; a3 += q4[c].w * kv.w;
        }
        s[jj] = (a0 + a1 + a2 + a3) * 0.125f;
        tmax = fmaxf(tmax, s[jj]);
      }
      const float mnew = fmaxf(m, tmax);
      const float corr = __expf(m - mnew);
      l *= corr;
      #pragma unroll
      for (int c = 0; c < 16; ++c) {
        o4[c].x *= corr; o4[c].y *= corr; o4[c].z *= corr; o4[c].w *= corr;
      }
      float psum = 0.f;
      #pragma unroll
      for (int jj = 0; jj < 16; ++jj) {
        const int j = jc * 16 + jj;
        const float p = __expf(s[jj] - mnew);
        psum += p;
        const float4* vr = reinterpret_cast<const float4*>(&Vs[j][0]);
        #pragma unroll
        for (int c = 0; c < 16; ++c) {
          const float4 vv = vr[c];
          o4[c].x += p * vv.x; o4[c].y += p * vv.y;
          o4[c].z += p * vv.z; o4[c].w += p * vv.w;
        }
      }
      l += psum; m = mnew;
    }
    __syncthreads();
  }

  const float inv = 1.f / l;
  float* op = AO + ((size_t)b * SEQ + row) * DM + h * HD;
  #pragma unroll
  for (int c = 0; c < 16; ++c) {
    float4 o = o4[c];
    o.x *= inv; o.y *= inv; o.z *= inv; o.w *= inv;
    reinterpret_cast<float4*>(op)[c] = o;
  }
}

// ---------------------------------------------------------------------------
// Output projection: OUT[r,c] = sum_d AO[r,d] * Wp[d,c] + bp[c]
// grid (ROWS/64, DM/64), block 256
// ---------------------------------------------------------------------------
__global__ __launch_bounds__(256) void proj_out(
    const float* __restrict__ X, const float* __restrict__ W,
    const float* __restrict__ bias, float* __restrict__ OUT)
{
  __shared__ float As[32][68];
  __shared__ float Bs[32][64];
  const int tid = threadIdx.x;
  const int tx = tid & 15, ty = tid >> 4;
  const int row0 = blockIdx.x * 64;
  const int col0 = blockIdx.y * 64;
  float acc[4][4] = {};

  #pragma unroll 1
  for (int k0 = 0; k0 < DM; k0 += 32) {
    #pragma unroll
    for (int it = 0; it < 2; ++it) {
      const int i = tid + it * 256;
      const int r = i >> 3, c = (i & 7) * 4;
      const float4 v = *reinterpret_cast<const float4*>(
          X + (size_t)(row0 + r) * DM + k0 + c);
      As[c + 0][r] = v.x; As[c + 1][r] = v.y;
      As[c + 2][r] = v.z; As[c + 3][r] = v.w;
    }
    #pragma unroll
    for (int it = 0; it < 2; ++it) {
      const int i = tid + it * 256;
      const int kk = i >> 4, j = (i & 15) * 4;
      *reinterpret_cast<float4*>(&Bs[kk][j]) =
          *reinterpret_cast<const float4*>(W + (size_t)(k0 + kk) * DM + col0 + j);
    }
    __syncthreads();
    #pragma unroll
    for (int kk = 0; kk < 32; ++kk) {
      const float4 a = *reinterpret_cast<const float4*>(&As[kk][ty * 4]);
      const float4 b = *reinterpret_cast<const float4*>(&Bs[kk][tx * 4]);
      const float av[4] = {a.x, a.y, a.z, a.w};
      const float bv[4] = {b.x, b.y, b.z, b.w};
      #pragma unroll
      for (int i = 0; i < 4; ++i)
        #pragma unroll
        for (int j = 0; j < 4; ++j) acc[i][j] += av[i] * bv[j];
    }
    __syncthreads();
  }

  const float4 bz = *reinterpret_cast<const float4*>(bias + col0 + tx * 4);
  #pragma unroll
  for (int i = 0; i < 4; ++i) {
    const int rg = row0 + ty * 4 + i;
    float4 o;
    o.x = acc[i][0] + bz.x; o.y = acc[i][1] + bz.y;
    o.z = acc[i][2] + bz.z; o.w = acc[i][3] + bz.w;
    *reinterpret_cast<float4*>(OUT + (size_t)rg * DM + col0 + tx * 4) = o;
  }
}

}  // namespace

extern "C" void kernel_launch(void* const* d_in, const int* in_sizes, int n_in,
                              void* d_out, int out_size, void* d_ws, size_t ws_size,
                              hipStream_t stream) {
  const float* query = (const float*)d_in[0];
  const float* key   = (const float*)d_in[1];
  const float* value = (const float*)d_in[2];
  const float* Wq    = (const float*)d_in[3];
  const float* bq    = (const float*)d_in[4];
  const float* Wk    = (const float*)d_in[5];
  const float* bk    = (const float*)d_in[6];
  const float* Wv    = (const float*)d_in[7];
  const float* bv    = (const float*)d_in[8];
  const float* Wp    = (const float*)d_in[9];
  const float* bp    = (const float*)d_in[10];
  float* out = (float*)d_out;

  // Workspace layout (fp32): Q, K, V: [NB*NH, SEQ, HD]; AO: [NB, SEQ, DM]
  const size_t BUF = (size_t)NB * NH * SEQ * HD * sizeof(float);  // 32 MiB
  char* ws = (char*)d_ws;
  float* Qb = (float*)(ws);
  float* Kb = (float*)(ws + BUF);
  float* Vb = (float*)(ws + 2 * BUF);
  float* AO = (float*)(ws + 3 * BUF);

  dim3 blk(256);
  dim3 gproj(ROWS / 64, NH);
  proj_qkv<<<gproj, blk, 0, stream>>>(query, Wq, bq, Qb);
  proj_qkv<<<gproj, blk, 0, stream>>>(key,   Wk, bk, Kb);
  proj_qkv<<<gproj, blk, 0, stream>>>(value, Wv, bv, Vb);

  dim3 gattn(SEQ / 256, NH, NB);
  attn<<<gattn, blk, 0, stream>>>(Qb, Kb, Vb, AO);

  dim3 gout(ROWS / 64, DM / 64);
  proj_out<<<gout, blk, 0, stream>>>(AO, Wp, bp, out);
}

// Round 2
// 409.632 us; speedup vs baseline: 6.1129x; 6.1129x over previous
//
#include <hip/hip_runtime.h>

namespace {
constexpr int DM = 1024;
constexpr int NH = 16;
constexpr int SEQ = 2048;
constexpr int NB = 4;

typedef float f32x4 __attribute__((ext_vector_type(4)));
typedef short bf16x8 __attribute__((ext_vector_type(8)));

__device__ inline ushort f2bf(float x) {
  union { float f; unsigned u; } v; v.f = x;
  unsigned r = v.u + 0x7fffu + ((v.u >> 16) & 1u);
  return (ushort)(r >> 16);
}

__device__ inline bf16x8 pack8(float4 a, float4 b) {
  union { bf16x8 v; ushort u[8]; } t;
  t.u[0] = f2bf(a.x); t.u[1] = f2bf(a.y); t.u[2] = f2bf(a.z); t.u[3] = f2bf(a.w);
  t.u[4] = f2bf(b.x); t.u[5] = f2bf(b.y); t.u[6] = f2bf(b.z); t.u[7] = f2bf(b.w);
  return t.v;
}

// ---------------------------------------------------------------------------
// W prep: Wt[col][d] (bf16) = W[h][d][k] (mode 0, col=h*64+k) or Wp[d][col] (mode 1)
// ---------------------------------------------------------------------------
__global__ __launch_bounds__(256) void prep_w(
    const float* __restrict__ W, ushort* __restrict__ Wt, int mode)
{
  const int gid = blockIdx.x * 256 + threadIdx.x;   // 0 .. 1024*256
  const int col = gid >> 8;
  const int d0 = (gid & 255) * 4;
  #pragma unroll
  for (int j = 0; j < 4; ++j) {
    const int d = d0 + j;
    const float v = (mode == 0)
        ? W[((size_t)(col >> 6) * DM + d) * 64 + (col & 63)]
        : W[(size_t)d * DM + col];
    Wt[(size_t)col * DM + d] = f2bf(v);
  }
}

// ---------------------------------------------------------------------------
// MFMA GEMM: C[row][col] = A[row][:] . Wt[col][:] + bias[col]
// A: [8192][1024] fp32 (ASRC=0) or bf16 (ASRC=1). Wt: [1024][1024] bf16 (N-major).
// Tile 128x128, BK=64, 256 threads = 4 waves (2x2), each wave 64x64.
// OMODE 0: bf16 out [bh][s][hd] (row=b*2048+s, col=h*64+hd)
// OMODE 2: bf16 out transposed [bh][hd][s]
// OMODE 3: fp32 out [row][1024]
// ---------------------------------------------------------------------------
template<int ASRC, int OMODE>
__global__ __launch_bounds__(256) void gemm128(
    const void* __restrict__ Ap, const ushort* __restrict__ Bt,
    const float* __restrict__ bias, void* __restrict__ Out)
{
  __shared__ ushort As[128 * 64];
  __shared__ ushort Bs[128 * 64];
  const int tid = threadIdx.x;
  const int l = tid & 63, l15 = l & 15, l4 = l >> 4;
  const int wid = tid >> 6, wm = wid >> 1, wn = wid & 1;
  const int row0 = blockIdx.x * 128, col0 = blockIdx.y * 128;
  const int ra = tid >> 1, cb = (tid & 1) * 4;
  f32x4 acc[4][4] = {};

  for (int k0 = 0; k0 < DM; k0 += 64) {
    if (ASRC == 0) {
      const float* A = (const float*)Ap;
      const float* ap = A + (size_t)(row0 + ra) * DM + k0 + cb * 8;
      #pragma unroll
      for (int j = 0; j < 4; ++j) {
        const float4 v0 = *reinterpret_cast<const float4*>(ap + j * 8);
        const float4 v1 = *reinterpret_cast<const float4*>(ap + j * 8 + 4);
        *reinterpret_cast<bf16x8*>(&As[ra * 64 + (((cb + j) ^ (ra & 7)) << 3)]) =
            pack8(v0, v1);
      }
    } else {
      const ushort* A = (const ushort*)Ap;
      #pragma unroll
      for (int j = 0; j < 4; ++j) {
        const bf16x8 v = *reinterpret_cast<const bf16x8*>(
            A + (size_t)(row0 + ra) * DM + k0 + (cb + j) * 8);
        *reinterpret_cast<bf16x8*>(&As[ra * 64 + (((cb + j) ^ (ra & 7)) << 3)]) = v;
      }
    }
    #pragma unroll
    for (int j = 0; j < 4; ++j) {
      const bf16x8 v = *reinterpret_cast<const bf16x8*>(
          Bt + (size_t)(col0 + ra) * DM + k0 + (cb + j) * 8);
      *reinterpret_cast<bf16x8*>(&Bs[ra * 64 + (((cb + j) ^ (ra & 7)) << 3)]) = v;
    }
    __syncthreads();

    #pragma unroll
    for (int kc = 0; kc < 2; ++kc) {
      bf16x8 a[4], bfr[4];
      #pragma unroll
      for (int m = 0; m < 4; ++m) {
        const int rr = wm * 64 + m * 16 + l15;
        a[m] = *reinterpret_cast<const bf16x8*>(
            &As[rr * 64 + (((kc * 4 + l4) ^ (rr & 7)) << 3)]);
      }
      #pragma unroll
      for (int n = 0; n < 4; ++n) {
        const int cc = wn * 64 + n * 16 + l15;
        bfr[n] = *reinterpret_cast<const bf16x8*>(
            &Bs[cc * 64 + (((kc * 4 + l4) ^ (cc & 7)) << 3)]);
      }
      #pragma unroll
      for (int m = 0; m < 4; ++m)
        #pragma unroll
        for (int n = 0; n < 4; ++n)
          acc[m][n] = __builtin_amdgcn_mfma_f32_16x16x32_bf16(
              a[m], bfr[n], acc[m][n], 0, 0, 0);
    }
    __syncthreads();
  }

  #pragma unroll
  for (int m = 0; m < 4; ++m) {
    #pragma unroll
    for (int n = 0; n < 4; ++n) {
      const int col = col0 + wn * 64 + n * 16 + l15;
      const float bz = bias[col];
      #pragma unroll
      for (int r = 0; r < 4; ++r) {
        const int row = row0 + wm * 64 + m * 16 + l4 * 4 + r;
        const float v = acc[m][n][r] + bz;
        if (OMODE == 0) {
          const size_t o =
              ((size_t)((row >> 11) * NH + (col >> 6)) * SEQ + (row & 2047)) * 64
              + (col & 63);
          ((ushort*)Out)[o] = f2bf(v);
        } else if (OMODE == 2) {
          const size_t o =
              ((size_t)((row >> 11) * NH + (col >> 6)) * 64 + (col & 63)) * SEQ
              + (row & 2047);
          ((ushort*)Out)[o] = f2bf(v);
        } else {
          ((float*)Out)[(size_t)row * DM + col] = v;
        }
      }
    }
  }
}

// ---------------------------------------------------------------------------
// Flash attention, MFMA. Q,K: bf16 [bh][s][64]; Vt: bf16 [bh][64][s].
// AO: bf16 [b][s][1024]. Block: 512 thr = 8 waves; wave = 16 q rows; KV tile 64.
// grid (SEQ/128, NH, NB)
// ---------------------------------------------------------------------------
__global__ __launch_bounds__(512) void attn_mfma(
    const ushort* __restrict__ Q, const ushort* __restrict__ K,
    const ushort* __restrict__ Vt, ushort* __restrict__ AO)
{
  __shared__ ushort Ks[64 * 64];
  __shared__ ushort Vs[64 * 64];
  __shared__ ushort Pl[8 * 16 * 64];
  const int tid = threadIdx.x;
  const int w = tid >> 6, l = tid & 63;
  const int l15 = l & 15, l4 = l >> 4, l7 = l & 7;
  const int h = blockIdx.y, b = blockIdx.z;
  const int bh = b * NH + h;
  const int qbase = blockIdx.x * 128 + w * 16;
  ushort* Pw = Pl + w * (16 * 64);

  bf16x8 qf[2];
  {
    const ushort* qp = Q + ((size_t)bh * SEQ + qbase + l15) * 64 + l4 * 8;
    qf[0] = *reinterpret_cast<const bf16x8*>(qp);
    qf[1] = *reinterpret_cast<const bf16x8*>(qp + 32);
  }

  f32x4 oacc[4] = {};
  float m2[4], lsum[4];
  #pragma unroll
  for (int r = 0; r < 4; ++r) { m2[r] = -1e30f; lsum[r] = 0.f; }

  for (int kt = 0; kt < SEQ / 64; ++kt) {
    {
      const int r = tid >> 3, c = tid & 7;
      const bf16x8 kv = *reinterpret_cast<const bf16x8*>(
          K + ((size_t)bh * SEQ + kt * 64 + r) * 64 + c * 8);
      *reinterpret_cast<bf16x8*>(&Ks[r * 64 + ((c ^ (r & 7)) << 3)]) = kv;
      const bf16x8 vv = *reinterpret_cast<const bf16x8*>(
          Vt + ((size_t)bh * 64 + r) * SEQ + kt * 64 + c * 8);
      *reinterpret_cast<bf16x8*>(&Vs[r * 64 + ((c ^ (r & 7)) << 3)]) = vv;
    }
    __syncthreads();

    // QK^T: sacc[c] covers kv cols c*16..c*16+15 for this wave's 16 q rows
    f32x4 sacc[4] = {};
    #pragma unroll
    for (int kc = 0; kc < 2; ++kc) {
      #pragma unroll
      for (int c = 0; c < 4; ++c) {
        const int kvi = c * 16 + l15;
        const bf16x8 bf = *reinterpret_cast<const bf16x8*>(
            &Ks[kvi * 64 + (((kc * 4 + l4) ^ (kvi & 7)) << 3)]);
        sacc[c] = __builtin_amdgcn_mfma_f32_16x16x32_bf16(qf[kc], bf, sacc[c], 0, 0, 0);
      }
    }

    // online softmax in log2 domain; write P (bf16) to per-wave LDS
    constexpr float SC = 0.125f * 1.44269504088896340736f;
    #pragma unroll
    for (int r = 0; r < 4; ++r) {
      const float s0 = sacc[0][r] * SC, s1 = sacc[1][r] * SC;
      const float s2 = sacc[2][r] * SC, s3 = sacc[3][r] * SC;
      float t = fmaxf(fmaxf(s0, s1), fmaxf(s2, s3));
      t = fmaxf(t, __shfl_xor(t, 1));
      t = fmaxf(t, __shfl_xor(t, 2));
      t = fmaxf(t, __shfl_xor(t, 4));
      t = fmaxf(t, __shfl_xor(t, 8));
      const float mn = fmaxf(m2[r], t);
      const float corr = exp2f(m2[r] - mn);
      m2[r] = mn;
      const float p0 = exp2f(s0 - mn), p1 = exp2f(s1 - mn);
      const float p2 = exp2f(s2 - mn), p3 = exp2f(s3 - mn);
      float ps = p0 + p1 + p2 + p3;
      ps += __shfl_xor(ps, 1);
      ps += __shfl_xor(ps, 2);
      ps += __shfl_xor(ps, 4);
      ps += __shfl_xor(ps, 8);
      lsum[r] = lsum[r] * corr + ps;
      #pragma unroll
      for (int c = 0; c < 4; ++c) oacc[c][r] *= corr;
      const int q = l4 * 4 + r;
      const int base = q * 64, sw = q & 7, ch0 = l15 >> 3;
      Pw[base + (((ch0 + 0) ^ sw) << 3) + l7] = f2bf(p0);
      Pw[base + (((ch0 + 2) ^ sw) << 3) + l7] = f2bf(p1);
      Pw[base + (((ch0 + 4) ^ sw) << 3) + l7] = f2bf(p2);
      Pw[base + (((ch0 + 6) ^ sw) << 3) + l7] = f2bf(p3);
    }

    // PV: oacc[c] covers hd cols c*16..c*16+15
    #pragma unroll
    for (int kc = 0; kc < 2; ++kc) {
      const bf16x8 af = *reinterpret_cast<const bf16x8*>(
          &Pw[l15 * 64 + (((kc * 4 + l4) ^ (l15 & 7)) << 3)]);
      #pragma unroll
      for (int c = 0; c < 4; ++c) {
        const int hd = c * 16 + l15;
        const bf16x8 bf = *reinterpret_cast<const bf16x8*>(
            &Vs[hd * 64 + (((kc * 4 + l4) ^ (hd & 7)) << 3)]);
        oacc[c] = __builtin_amdgcn_mfma_f32_16x16x32_bf16(af, bf, oacc[c], 0, 0, 0);
      }
    }
    __syncthreads();
  }

  #pragma unroll
  for (int r = 0; r < 4; ++r) {
    const float inv = 1.f / lsum[r];
    const int s = qbase + l4 * 4 + r;
    #pragma unroll
    for (int c = 0; c < 4; ++c) {
      AO[((size_t)b * SEQ + s) * DM + h * 64 + c * 16 + l15] =
          f2bf(oacc[c][r] * inv);
    }
  }
}

}  // namespace

extern "C" void kernel_launch(void* const* d_in, const int* in_sizes, int n_in,
                              void* d_out, int out_size, void* d_ws, size_t ws_size,
                              hipStream_t stream) {
  const float* query = (const float*)d_in[0];
  const float* key   = (const float*)d_in[1];
  const float* value = (const float*)d_in[2];
  const float* Wq    = (const float*)d_in[3];
  const float* bq    = (const float*)d_in[4];
  const float* Wk    = (const float*)d_in[5];
  const float* bk    = (const float*)d_in[6];
  const float* Wv    = (const float*)d_in[7];
  const float* bv    = (const float*)d_in[8];
  const float* Wp    = (const float*)d_in[9];
  const float* bp    = (const float*)d_in[10];
  float* out = (float*)d_out;

  // Workspace (bf16 buffers): 4x Wt (2 MiB) + Q/K/Vt (16 MiB) + AO (16 MiB) = 72 MiB
  char* ws = (char*)d_ws;
  const size_t MB = 1024 * 1024;
  ushort* Wtq = (ushort*)(ws + 0 * MB);
  ushort* Wtk = (ushort*)(ws + 2 * MB);
  ushort* Wtv = (ushort*)(ws + 4 * MB);
  ushort* Wtp = (ushort*)(ws + 6 * MB);
  ushort* Qb  = (ushort*)(ws + 8 * MB);
  ushort* Kb  = (ushort*)(ws + 24 * MB);
  ushort* Vtb = (ushort*)(ws + 40 * MB);
  ushort* AO  = (ushort*)(ws + 56 * MB);

  prep_w<<<1024, 256, 0, stream>>>(Wq, Wtq, 0);
  prep_w<<<1024, 256, 0, stream>>>(Wk, Wtk, 0);
  prep_w<<<1024, 256, 0, stream>>>(Wv, Wtv, 0);
  prep_w<<<1024, 256, 0, stream>>>(Wp, Wtp, 1);

  dim3 blk(256);
  dim3 gg(64, 8);
  gemm128<0, 0><<<gg, blk, 0, stream>>>(query, Wtq, bq, Qb);
  gemm128<0, 0><<<gg, blk, 0, stream>>>(key,   Wtk, bk, Kb);
  gemm128<0, 2><<<gg, blk, 0, stream>>>(value, Wtv, bv, Vtb);

  attn_mfma<<<dim3(SEQ / 128, NH, NB), dim3(512), 0, stream>>>(Qb, Kb, Vtb, AO);

  gemm128<1, 3><<<gg, blk, 0, stream>>>(AO, Wtp, bp, out);
}

// Round 3
// 285.123 us; speedup vs baseline: 8.7823x; 1.4367x over previous
//
#include <hip/hip_runtime.h>

namespace {
constexpr int DM = 1024;
constexpr int NH = 16;
constexpr int SEQ = 2048;
constexpr int NB = 4;

typedef float f32x4 __attribute__((ext_vector_type(4)));
typedef short bf16x8 __attribute__((ext_vector_type(8)));

__device__ inline ushort f2bf(float x) {
  union { float f; unsigned u; } v; v.f = x;
  unsigned r = v.u + 0x7fffu + ((v.u >> 16) & 1u);
  return (ushort)(r >> 16);
}

__device__ inline unsigned cvt_pk_bf16(float lo, float hi) {
  unsigned r;
  asm("v_cvt_pk_bf16_f32 %0, %1, %2" : "=v"(r) : "v"(lo), "v"(hi));
  return r;
}

__device__ inline float fast_exp2(float x) {
  float r;
  asm("v_exp_f32 %0, %1" : "=v"(r) : "v"(x));
  return r;
}

__device__ inline bf16x8 pack8(float4 a, float4 b) {
  union { bf16x8 v; unsigned u[4]; } t;
  t.u[0] = cvt_pk_bf16(a.x, a.y); t.u[1] = cvt_pk_bf16(a.z, a.w);
  t.u[2] = cvt_pk_bf16(b.x, b.y); t.u[3] = cvt_pk_bf16(b.z, b.w);
  return t.v;
}

// ---------------------------------------------------------------------------
// W prep via LDS tile transpose (coalesced both sides).
// mode 0: W[h][d][k] -> Wt[h*64+k][d];  mode 1: W[d][c] -> Wt[c][d]
// grid (DM/64, 16), block 256
// ---------------------------------------------------------------------------
__global__ __launch_bounds__(256) void prep_w(
    const float* __restrict__ W, ushort* __restrict__ Wt, int mode)
{
  __shared__ ushort T[64][72];
  const int t = threadIdx.x;
  const int d0 = blockIdx.x * 64;
  const int colbase = blockIdx.y * 64;
  #pragma unroll
  for (int pass = 0; pass < 4; ++pass) {
    const int dl = (t >> 4) + pass * 16;
    const int k = (t & 15) * 4;
    const size_t src = (mode == 0)
        ? (size_t)colbase * 1024 + (size_t)(d0 + dl) * 64 + k
        : (size_t)(d0 + dl) * 1024 + colbase + k;
    const float4 v = *reinterpret_cast<const float4*>(W + src);
    T[k + 0][dl] = f2bf(v.x); T[k + 1][dl] = f2bf(v.y);
    T[k + 2][dl] = f2bf(v.z); T[k + 3][dl] = f2bf(v.w);
  }
  __syncthreads();
  const int k = t >> 2, dp = (t & 3) * 16;
  ushort* dst = Wt + (size_t)(colbase + k) * DM + d0 + dp;
  *reinterpret_cast<bf16x8*>(dst) = *reinterpret_cast<const bf16x8*>(&T[k][dp]);
  *reinterpret_cast<bf16x8*>(dst + 8) = *reinterpret_cast<const bf16x8*>(&T[k][dp + 8]);
}

// ---------------------------------------------------------------------------
// MFMA GEMM: C[row][col] = A[row][:] . Wt[col][:] + bias[col]
// Tile 128x128, BK=64, 4 waves (2x2). OMODE 0: bf16 [bh][s][hd];
// OMODE 2: bf16 [bh][hd][s] (packed b64 stores); OMODE 3: fp32 [row][1024].
// ---------------------------------------------------------------------------
template<int ASRC, int OMODE>
__global__ __launch_bounds__(256) void gemm128(
    const void* __restrict__ Ap, const ushort* __restrict__ Bt,
    const float* __restrict__ bias, void* __restrict__ Out)
{
  __shared__ ushort As[128 * 64];
  __shared__ ushort Bs[128 * 64];
  const int tid = threadIdx.x;
  const int l = tid & 63, l15 = l & 15, l4 = l >> 4;
  const int wid = tid >> 6, wm = wid >> 1, wn = wid & 1;
  const int row0 = blockIdx.x * 128, col0 = blockIdx.y * 128;
  const int ra = tid >> 1, cb = (tid & 1) * 4;
  f32x4 acc[4][4] = {};

  for (int k0 = 0; k0 < DM; k0 += 64) {
    if (ASRC == 0) {
      const float* A = (const float*)Ap;
      const float* ap = A + (size_t)(row0 + ra) * DM + k0 + cb * 8;
      #pragma unroll
      for (int j = 0; j < 4; ++j) {
        const float4 v0 = *reinterpret_cast<const float4*>(ap + j * 8);
        const float4 v1 = *reinterpret_cast<const float4*>(ap + j * 8 + 4);
        *reinterpret_cast<bf16x8*>(&As[ra * 64 + (((cb + j) ^ (ra & 7)) << 3)]) =
            pack8(v0, v1);
      }
    } else {
      const ushort* A = (const ushort*)Ap;
      #pragma unroll
      for (int j = 0; j < 4; ++j) {
        const bf16x8 v = *reinterpret_cast<const bf16x8*>(
            A + (size_t)(row0 + ra) * DM + k0 + (cb + j) * 8);
        *reinterpret_cast<bf16x8*>(&As[ra * 64 + (((cb + j) ^ (ra & 7)) << 3)]) = v;
      }
    }
    #pragma unroll
    for (int j = 0; j < 4; ++j) {
      const bf16x8 v = *reinterpret_cast<const bf16x8*>(
          Bt + (size_t)(col0 + ra) * DM + k0 + (cb + j) * 8);
      *reinterpret_cast<bf16x8*>(&Bs[ra * 64 + (((cb + j) ^ (ra & 7)) << 3)]) = v;
    }
    __syncthreads();

    #pragma unroll
    for (int kc = 0; kc < 2; ++kc) {
      bf16x8 a[4], bfr[4];
      #pragma unroll
      for (int m = 0; m < 4; ++m) {
        const int rr = wm * 64 + m * 16 + l15;
        a[m] = *reinterpret_cast<const bf16x8*>(
            &As[rr * 64 + (((kc * 4 + l4) ^ (rr & 7)) << 3)]);
      }
      #pragma unroll
      for (int n = 0; n < 4; ++n) {
        const int cc = wn * 64 + n * 16 + l15;
        bfr[n] = *reinterpret_cast<const bf16x8*>(
            &Bs[cc * 64 + (((kc * 4 + l4) ^ (cc & 7)) << 3)]);
      }
      #pragma unroll
      for (int m = 0; m < 4; ++m)
        #pragma unroll
        for (int n = 0; n < 4; ++n)
          acc[m][n] = __builtin_amdgcn_mfma_f32_16x16x32_bf16(
              a[m], bfr[n], acc[m][n], 0, 0, 0);
    }
    __syncthreads();
  }

  #pragma unroll
  for (int m = 0; m < 4; ++m) {
    #pragma unroll
    for (int n = 0; n < 4; ++n) {
      const int col = col0 + wn * 64 + n * 16 + l15;
      const float bz = bias[col];
      if (OMODE == 2) {
        const int row = row0 + wm * 64 + m * 16 + l4 * 4;
        const unsigned w0 = cvt_pk_bf16(acc[m][n][0] + bz, acc[m][n][1] + bz);
        const unsigned w1 = cvt_pk_bf16(acc[m][n][2] + bz, acc[m][n][3] + bz);
        const size_t o =
            ((size_t)((row >> 11) * NH + (col >> 6)) * 64 + (col & 63)) * SEQ
            + (row & 2047);
        *reinterpret_cast<uint2*>((ushort*)Out + o) = make_uint2(w0, w1);
      } else {
        #pragma unroll
        for (int r = 0; r < 4; ++r) {
          const int row = row0 + wm * 64 + m * 16 + l4 * 4 + r;
          const float v = acc[m][n][r] + bz;
          if (OMODE == 0) {
            const size_t o =
                ((size_t)((row >> 11) * NH + (col >> 6)) * SEQ + (row & 2047)) * 64
                + (col & 63);
            ((ushort*)Out)[o] = f2bf(v);
          } else {
            ((float*)Out)[(size_t)row * DM + col] = v;
          }
        }
      }
    }
  }
}

// ---------------------------------------------------------------------------
// Flash attention, MFMA, defer-max + lazy lsum + packed P path.
// Q,K: bf16 [bh][s][64]; Vt: bf16 [bh][64][s]; AO: bf16 [b][s][1024].
// 512 thr = 8 waves, 16 q rows/wave, KV tile 64. grid (SEQ/128, NH, NB).
// P & Vs use kv-permuted storage: i = 4*l15+t <-> kv = t*16+l15, with
// 8B-chunk swizzle chunk' = chunk ^ ((row&7)<<1) (preserves 16B read pairs).
// ---------------------------------------------------------------------------
__global__ __launch_bounds__(512) void attn_mfma(
    const ushort* __restrict__ Q, const ushort* __restrict__ K,
    const ushort* __restrict__ Vt, ushort* __restrict__ AO)
{
  __shared__ ushort Ks[64 * 64];
  __shared__ ushort Vs[64 * 64];
  __shared__ ushort Pl[8 * 16 * 64];
  const int tid = threadIdx.x;
  const int w = tid >> 6, l = tid & 63;
  const int l15 = l & 15, l4 = l >> 4;
  const int h = blockIdx.y, b = blockIdx.z;
  const int bh = b * NH + h;
  const int qbase = blockIdx.x * 128 + w * 16;
  ushort* Pw = Pl + w * (16 * 64);
  const int swzv = (l15 & 7) << 1;

  bf16x8 qf[2];
  {
    const ushort* qp = Q + ((size_t)bh * SEQ + qbase + l15) * 64 + l4 * 8;
    qf[0] = *reinterpret_cast<const bf16x8*>(qp);
    qf[1] = *reinterpret_cast<const bf16x8*>(qp + 32);
  }

  f32x4 oacc[4] = {};
  float m2[4], lsum[4];
  #pragma unroll
  for (int r = 0; r < 4; ++r) { m2[r] = -1e30f; lsum[r] = 0.f; }

  const int kr = tid >> 3, kc8 = tid & 7;   // staging coords

  for (int kt = 0; kt < SEQ / 64; ++kt) {
    {
      // K tile: [kv][d], 8-chunk xor swizzle
      const bf16x8 kv = *reinterpret_cast<const bf16x8*>(
          K + ((size_t)bh * SEQ + kt * 64 + kr) * 64 + kc8 * 8);
      *reinterpret_cast<bf16x8*>(&Ks[kr * 64 + ((kc8 ^ (kr & 7)) << 3)]) = kv;
      // V tile: [hd][i] with kv permutation; regather pairs into storage order
      const ushort* vrow = Vt + ((size_t)bh * 64 + kr) * SEQ + kt * 64;
      const unsigned a0 = *reinterpret_cast<const unsigned*>(vrow + 2 * kc8);
      const unsigned a1 = *reinterpret_cast<const unsigned*>(vrow + 2 * kc8 + 16);
      const unsigned a2 = *reinterpret_cast<const unsigned*>(vrow + 2 * kc8 + 32);
      const unsigned a3 = *reinterpret_cast<const unsigned*>(vrow + 2 * kc8 + 48);
      union { bf16x8 v; unsigned u[4]; } pk;
      pk.u[0] = (a0 & 0xffffu) | (a1 << 16);
      pk.u[1] = (a2 & 0xffffu) | (a3 << 16);
      pk.u[2] = (a0 >> 16) | (a1 & 0xffff0000u);
      pk.u[3] = (a2 >> 16) | (a3 & 0xffff0000u);
      *reinterpret_cast<bf16x8*>(
          &Vs[kr * 64 + (((2 * kc8) ^ ((kr & 7) << 1)) << 2)]) = pk.v;
    }
    __syncthreads();

    // QK^T
    f32x4 sacc[4] = {};
    __builtin_amdgcn_s_setprio(1);
    #pragma unroll
    for (int kc = 0; kc < 2; ++kc) {
      #pragma unroll
      for (int c = 0; c < 4; ++c) {
        const int kvi = c * 16 + l15;
        const bf16x8 bf = *reinterpret_cast<const bf16x8*>(
            &Ks[kvi * 64 + (((kc * 4 + l4) ^ (kvi & 7)) << 3)]);
        sacc[c] = __builtin_amdgcn_mfma_f32_16x16x32_bf16(qf[kc], bf, sacc[c], 0, 0, 0);
      }
    }
    __builtin_amdgcn_s_setprio(0);

    // online softmax, log2 domain, defer-max (THR=8) + lazy per-lane lsum
    constexpr float SC = 0.125f * 1.44269504088896340736f;
    #pragma unroll
    for (int r = 0; r < 4; ++r) {
      const float s0 = sacc[0][r] * SC, s1 = sacc[1][r] * SC;
      const float s2 = sacc[2][r] * SC, s3 = sacc[3][r] * SC;
      const float pmax = fmaxf(fmaxf(s0, s1), fmaxf(s2, s3));
      if (!__all(pmax <= m2[r] + 8.f)) {
        float t = pmax;
        t = fmaxf(t, __shfl_xor(t, 1));
        t = fmaxf(t, __shfl_xor(t, 2));
        t = fmaxf(t, __shfl_xor(t, 4));
        t = fmaxf(t, __shfl_xor(t, 8));
        const float mn = fmaxf(m2[r], t);
        const float corr = fast_exp2(m2[r] - mn);
        m2[r] = mn;
        lsum[r] *= corr;
        #pragma unroll
        for (int c = 0; c < 4; ++c) oacc[c][r] *= corr;
      }
      const float p0 = fast_exp2(s0 - m2[r]);
      const float p1 = fast_exp2(s1 - m2[r]);
      const float p2 = fast_exp2(s2 - m2[r]);
      const float p3 = fast_exp2(s3 - m2[r]);
      lsum[r] += (p0 + p1) + (p2 + p3);
      const unsigned w0 = cvt_pk_bf16(p0, p1);
      const unsigned w1 = cvt_pk_bf16(p2, p3);
      const int q = l4 * 4 + r;
      *reinterpret_cast<uint2*>(
          &Pw[q * 64 + ((l15 ^ ((q & 7) << 1)) << 2)]) = make_uint2(w0, w1);
    }

    // PV (kv-permuted on both operands)
    __builtin_amdgcn_s_setprio(1);
    #pragma unroll
    for (int kc = 0; kc < 2; ++kc) {
      const int cb = 2 * (kc * 4 + l4);
      const bf16x8 af = *reinterpret_cast<const bf16x8*>(
          &Pw[l15 * 64 + ((cb ^ swzv) << 2)]);
      #pragma unroll
      for (int c = 0; c < 4; ++c) {
        const int hd = c * 16 + l15;
        const bf16x8 bf = *reinterpret_cast<const bf16x8*>(
            &Vs[hd * 64 + ((cb ^ swzv) << 2)]);
        oacc[c] = __builtin_amdgcn_mfma_f32_16x16x32_bf16(af, bf, oacc[c], 0, 0, 0);
      }
    }
    __builtin_amdgcn_s_setprio(0);
    __syncthreads();
  }

  #pragma unroll
  for (int r = 0; r < 4; ++r) {
    float ls = lsum[r];
    ls += __shfl_xor(ls, 1);
    ls += __shfl_xor(ls, 2);
    ls += __shfl_xor(ls, 4);
    ls += __shfl_xor(ls, 8);
    const float inv = 1.f / ls;
    const int s = qbase + l4 * 4 + r;
    #pragma unroll
    for (int c = 0; c < 4; ++c) {
      AO[((size_t)b * SEQ + s) * DM + h * 64 + c * 16 + l15] =
          f2bf(oacc[c][r] * inv);
    }
  }
}

}  // namespace

extern "C" void kernel_launch(void* const* d_in, const int* in_sizes, int n_in,
                              void* d_out, int out_size, void* d_ws, size_t ws_size,
                              hipStream_t stream) {
  const float* query = (const float*)d_in[0];
  const float* key   = (const float*)d_in[1];
  const float* value = (const float*)d_in[2];
  const float* Wq    = (const float*)d_in[3];
  const float* bq    = (const float*)d_in[4];
  const float* Wk    = (const float*)d_in[5];
  const float* bk    = (const float*)d_in[6];
  const float* Wv    = (const float*)d_in[7];
  const float* bv    = (const float*)d_in[8];
  const float* Wp    = (const float*)d_in[9];
  const float* bp    = (const float*)d_in[10];
  float* out = (float*)d_out;

  char* ws = (char*)d_ws;
  const size_t MB = 1024 * 1024;
  ushort* Wtq = (ushort*)(ws + 0 * MB);
  ushort* Wtk = (ushort*)(ws + 2 * MB);
  ushort* Wtv = (ushort*)(ws + 4 * MB);
  ushort* Wtp = (ushort*)(ws + 6 * MB);
  ushort* Qb  = (ushort*)(ws + 8 * MB);
  ushort* Kb  = (ushort*)(ws + 24 * MB);
  ushort* Vtb = (ushort*)(ws + 40 * MB);
  ushort* AO  = (ushort*)(ws + 56 * MB);

  dim3 gp(16, 16);
  prep_w<<<gp, 256, 0, stream>>>(Wq, Wtq, 0);
  prep_w<<<gp, 256, 0, stream>>>(Wk, Wtk, 0);
  prep_w<<<gp, 256, 0, stream>>>(Wv, Wtv, 0);
  prep_w<<<gp, 256, 0, stream>>>(Wp, Wtp, 1);

  dim3 blk(256);
  dim3 gg(64, 8);
  gemm128<0, 0><<<gg, blk, 0, stream>>>(query, Wtq, bq, Qb);
  gemm128<0, 0><<<gg, blk, 0, stream>>>(key,   Wtk, bk, Kb);
  gemm128<0, 2><<<gg, blk, 0, stream>>>(value, Wtv, bv, Vtb);

  attn_mfma<<<dim3(SEQ / 128, NH, NB), dim3(512), 0, stream>>>(Qb, Kb, Vtb, AO);

  gemm128<1, 3><<<gg, blk, 0, stream>>>(AO, Wtp, bp, out);
}